// Round 5
// baseline (607.009 us; speedup 1.0000x reference)
//
#include <hip/hip_runtime.h>

typedef unsigned short u16;
typedef __attribute__((ext_vector_type(8))) short short8;
typedef __attribute__((ext_vector_type(4))) short s4b;
typedef __attribute__((ext_vector_type(4))) float floatx4;

#define S_TOT 2304
#define N_SEQ 2048
#define T_SEQ 256
#define C_DIM 1024
#define NH 16
#define DH 64
#define SIX_C 6144

__device__ __forceinline__ u16 f2bf(float f) {
  union { float f; unsigned u; } v; v.f = f;
  unsigned r = (v.u + 0x7FFFu + ((v.u >> 16) & 1u)) >> 16;
  return (u16)r;
}
__device__ __forceinline__ float bf2f(u16 u) {
  union { unsigned u; float f; } v; v.u = ((unsigned)u) << 16; return v.f;
}
__device__ __forceinline__ unsigned fbits(float f) {
  union { float f; unsigned u; } v; v.f = f; return v.u;
}
// single-instruction exp2 (scores kept in log2 domain)
__device__ __forceinline__ float fexp2(float x) {
#if __has_builtin(__builtin_amdgcn_exp2f)
  return __builtin_amdgcn_exp2f(x);
#else
  return __expf(x * 0.6931471805599453f);
#endif
}

__device__ __forceinline__ void async16(const void* g, void* l) {
  __builtin_amdgcn_global_load_lds((const __attribute__((address_space(1))) void*)g,
                                   (__attribute__((address_space(3))) void*)l, 16, 0, 0);
}

__device__ __forceinline__ floatx4 zero4() {
  floatx4 z; z[0] = 0.f; z[1] = 0.f; z[2] = 0.f; z[3] = 0.f; return z;
}

// ---------------- adaLN modulation ----------------
__global__ __launch_bounds__(256)
void adaln_mod(const float* __restrict__ mod, const float* __restrict__ w,
               float* __restrict__ m) {
  __shared__ float sm[128];
  int b = blockIdx.y, kz = blockIdx.z;
  int tid = threadIdx.x;
  if (tid < 128) {
    float v = mod[b * C_DIM + kz * 128 + tid];
    sm[tid] = v / (1.f + __expf(-v));
  }
  __syncthreads();
  int j = blockIdx.x * 256 + tid;
  const float* wp = w + (size_t)(kz * 128) * SIX_C + j;
  float acc = 0.f;
  #pragma unroll 8
  for (int k = 0; k < 128; k++) acc += sm[k] * wp[(size_t)k * SIX_C];
  atomicAdd(&m[b * SIX_C + j], acc);
}

// ---------------- fused weight transpose + cast ----------------
__global__ __launch_bounds__(256)
void wtrans_all(const float* __restrict__ w0, const float* __restrict__ w1,
                const float* __restrict__ w2, const float* __restrict__ w3,
                const float* __restrict__ w4, const float* __restrict__ w5,
                u16* __restrict__ o0, u16* __restrict__ o1, u16* __restrict__ o2,
                u16* __restrict__ o3, u16* __restrict__ o4, u16* __restrict__ o5) {
  int bid = blockIdx.x;
  const float* W; u16* Wt; int K, N, bx, local;
  if (bid < 3072)       { W = w0; Wt = o0; K = 1024; N = 3072; bx = 96;  local = bid; }
  else if (bid < 4096)  { W = w1; Wt = o1; K = 1024; N = 1024; bx = 32;  local = bid - 3072; }
  else if (bid < 8192)  { W = w2; Wt = o2; K = 1024; N = 4096; bx = 128; local = bid - 4096; }
  else if (bid < 12288) { W = w3; Wt = o3; K = 4096; N = 1024; bx = 32;  local = bid - 8192; }
  else if (bid < 16384) { W = w4; Wt = o4; K = 1024; N = 4096; bx = 128; local = bid - 12288; }
  else                  { W = w5; Wt = o5; K = 4096; N = 1024; bx = 32;  local = bid - 16384; }
  int n0 = (local % bx) << 5, k0 = (local / bx) << 5;
  __shared__ float t[32][33];
  int tx = threadIdx.x & 31, ty = threadIdx.x >> 5;
  #pragma unroll
  for (int i = 0; i < 32; i += 8)
    t[ty + i][tx] = W[(size_t)(k0 + ty + i) * N + n0 + tx];
  __syncthreads();
  #pragma unroll
  for (int i = 0; i < 32; i += 8)
    Wt[(size_t)(n0 + ty + i) * K + k0 + tx] = f2bf(t[tx][ty + i]);
}

// ---------------- V[b,h,s,d] bf16 -> Vt[b,h,d,s] bf16 ----------------
__global__ __launch_bounds__(256)
void vtrans(const u16* __restrict__ V, u16* __restrict__ Vt) {
  __shared__ u16 t[64][65];
  int s0 = blockIdx.x << 6;
  int bh = blockIdx.y;
  const u16* src = V + (size_t)bh * S_TOT * DH;
  u16* dst = Vt + (size_t)bh * DH * S_TOT;
  int tid = threadIdx.x;
  #pragma unroll
  for (int i = 0; i < 16; i++) {
    int idx = tid + i * 256; int r = idx >> 6, c = idx & 63;
    t[r][c] = src[(size_t)(s0 + r) * DH + c];
  }
  __syncthreads();
  #pragma unroll
  for (int i = 0; i < 16; i++) {
    int idx = tid + i * 256; int r = idx >> 6, c = idx & 63;
    dst[(size_t)r * S_TOT + s0 + c] = t[c][r];
  }
}

// ---------------- LN + modulation -> bf16 ----------------
template<int SHIFT_OFS>
__global__ __launch_bounds__(256)
void ln_mod(const float* __restrict__ xin, const float* __restrict__ cin,
            const float* __restrict__ m, const float* __restrict__ ba,
            u16* __restrict__ xo, u16* __restrict__ co, u16* __restrict__ joint) {
  int row = blockIdx.x;
  int b = row / S_TOT, s = row - b * S_TOT;
  bool isx = (s < N_SEQ);
  size_t roff = isx ? (((size_t)(b * N_SEQ + s)) << 10)
                    : (((size_t)(b * T_SEQ + (s - N_SEQ))) << 10);
  const float* src = isx ? (xin + roff) : (cin + roff);
  int tid = threadIdx.x;
  float4 v = ((const float4*)src)[tid];
  float s1 = v.x + v.y + v.z + v.w;
  float s2 = v.x * v.x + v.y * v.y + v.z * v.z + v.w * v.w;
  #pragma unroll
  for (int o = 32; o; o >>= 1) { s1 += __shfl_xor(s1, o); s2 += __shfl_xor(s2, o); }
  __shared__ float red[8];
  int wv = tid >> 6, ln = tid & 63;
  if (ln == 0) { red[wv] = s1; red[4 + wv] = s2; }
  __syncthreads();
  s1 = red[0] + red[1] + red[2] + red[3];
  s2 = red[4] + red[5] + red[6] + red[7];
  float mu = s1 * (1.f / 1024.f);
  float var = s2 * (1.f / 1024.f) - mu * mu;
  float rstd = rsqrtf(var + 1e-6f);
  int c = tid << 2;
  const float* mb = m + b * SIX_C;
  float4 sc = *(const float4*)(mb + SHIFT_OFS + 1024 + c);
  float4 sb = *(const float4*)(ba + SHIFT_OFS + 1024 + c);
  float4 sh = *(const float4*)(mb + SHIFT_OFS + c);
  float4 hb = *(const float4*)(ba + SHIFT_OFS + c);
  float y0 = (v.x - mu) * rstd * (1.f + sc.x + sb.x) + sh.x + hb.x;
  float y1 = (v.y - mu) * rstd * (1.f + sc.y + sb.y) + sh.y + hb.y;
  float y2 = (v.z - mu) * rstd * (1.f + sc.z + sb.z) + sh.z + hb.z;
  float y3 = (v.w - mu) * rstd * (1.f + sc.w + sb.w) + sh.w + hb.w;
  unsigned long long o = (unsigned long long)f2bf(y0)
      | ((unsigned long long)f2bf(y1) << 16)
      | ((unsigned long long)f2bf(y2) << 32)
      | ((unsigned long long)f2bf(y3) << 48);
  u16* dst;
  if (SHIFT_OFS == 0) dst = joint + (((size_t)row) << 10);
  else dst = (isx ? xo : co) + roff;
  *(unsigned long long*)(dst + c) = o;
}

// ---------------- GEMM: MODE 0: qkv scatter, MODE 1: proj+res+gate ----------------
template<int MODE, int MT>
__global__ __launch_bounds__(256)
void gemm_k(const u16* __restrict__ A, const u16* __restrict__ Bt,
            const float* __restrict__ bias, int K,
            const float* __restrict__ mvec, const float* __restrict__ ba,
            const float* __restrict__ rx, const float* __restrict__ rc,
            float* __restrict__ ox, float* __restrict__ oc,
            u16* __restrict__ oq, u16* __restrict__ okd, u16* __restrict__ ov)
{
  __shared__ alignas(16) u16 lA[MT * 32];
  __shared__ alignas(16) u16 lB[128 * 32];
  int tid = threadIdx.x;
  int wave = tid >> 6, lane = tid & 63, quad = lane >> 4, l15 = lane & 15;
  int bx = blockIdx.x, by = blockIdx.y;
  const int MF = MT / 32;
  int wm = (wave >> 1) * (MT / 2), wn = (wave & 1) << 6;
  const u16* Ag = A + (size_t)(by * MT) * K;
  const u16* Bg = Bt + (size_t)(bx << 7) * K;
  floatx4 acc[MF][4];
  #pragma unroll
  for (int i = 0; i < MF; i++)
    #pragma unroll
    for (int j = 0; j < 4; j++) acc[i][j] = zero4();

  for (int k0 = 0; k0 < K; k0 += 32) {
    #pragma unroll
    for (int i = 0; i < MT / 64; i++) {
      int c = tid + (i << 8);
      async16(&Ag[(size_t)(c >> 2) * K + k0 + ((c & 3) << 3)], &lA[(size_t)c << 3]);
    }
    #pragma unroll
    for (int i = 0; i < 2; i++) {
      int c = tid + (i << 8);
      async16(&Bg[(size_t)(c >> 2) * K + k0 + ((c & 3) << 3)], &lB[(size_t)c << 3]);
    }
    __syncthreads();
    short8 af[MF], bfr[4];
    #pragma unroll
    for (int i = 0; i < MF; i++)
      af[i] = *(const short8*)&lA[(wm + (i << 4) + l15) * 32 + (quad << 3)];
    #pragma unroll
    for (int i = 0; i < 4; i++)
      bfr[i] = *(const short8*)&lB[(wn + (i << 4) + l15) * 32 + (quad << 3)];
    #pragma unroll
    for (int mi = 0; mi < MF; mi++)
      #pragma unroll
      for (int ni = 0; ni < 4; ni++)
        acc[mi][ni] = __builtin_amdgcn_mfma_f32_16x16x32_bf16(af[mi], bfr[ni], acc[mi][ni], 0, 0, 0);
    __syncthreads();
  }

  #pragma unroll
  for (int mi = 0; mi < MF; mi++) {
    #pragma unroll
    for (int r = 0; r < 4; r++) {
      int rg = by * MT + wm + (mi << 4) + (quad << 2) + r;
      int b = rg / S_TOT; int s = rg - b * S_TOT;
      if (MODE == 0) {
        #pragma unroll
        for (int ni = 0; ni < 4; ni++) {
          int col = (bx << 7) + wn + (ni << 4) + l15;
          float val = acc[mi][ni][r] + bias[col];
          int part = col >> 10, h = (col >> 6) & 15, d = col & 63;
          u16* dst = (part == 0) ? oq : (part == 1 ? okd : ov);
          dst[(((size_t)(b * NH + h)) * S_TOT + s) * DH + d] = f2bf(val);
        }
      } else {
        #pragma unroll
        for (int ni = 0; ni < 4; ni++) {
          int col = (bx << 7) + wn + (ni << 4) + l15;
          float val = acc[mi][ni][r] + bias[col];
          float g = mvec[b * SIX_C + 2048 + col] + ba[2048 + col];
          if (s < N_SEQ) {
            size_t idx = (((size_t)(b * N_SEQ + s)) << 10) + col;
            ox[idx] = rx[idx] + val * g;
          } else {
            size_t idx = (((size_t)(b * T_SEQ + (s - N_SEQ))) << 10) + col;
            oc[idx] = rc[idx] + val * g;
          }
        }
      }
    }
  }
}

// ---------------- fused MLP layer 1: [xln2;cln2] @ {ws1|wd1} + gelu|silu -> h1 ----------
__global__ __launch_bounds__(256)
void mlp1(const u16* __restrict__ Ax, const u16* __restrict__ Ac,
          const u16* __restrict__ Bx, const u16* __restrict__ Bc,
          const float* __restrict__ biasx, const float* __restrict__ biasc,
          u16* __restrict__ h1) {
  bool isx = (blockIdx.y < 32);
  const u16* A = isx ? (Ax + (size_t)(blockIdx.y << 7) * 1024)
                     : (Ac + (size_t)((blockIdx.y - 32) << 7) * 1024);
  const u16* Bt = isx ? Bx : Bc;
  const float* bias = isx ? biasx : biasc;
  const int K = 1024;
  __shared__ alignas(16) u16 lA[128 * 32];
  __shared__ alignas(16) u16 lB[128 * 32];
  int tid = threadIdx.x;
  int wave = tid >> 6, lane = tid & 63, quad = lane >> 4, l15 = lane & 15;
  int bx = blockIdx.x;
  int wm = (wave >> 1) << 6, wn = (wave & 1) << 6;
  const u16* Bg = Bt + (size_t)(bx << 7) * K;
  floatx4 acc[4][4];
  #pragma unroll
  for (int i = 0; i < 4; i++)
    #pragma unroll
    for (int j = 0; j < 4; j++) acc[i][j] = zero4();

  for (int k0 = 0; k0 < K; k0 += 32) {
    #pragma unroll
    for (int i = 0; i < 2; i++) {
      int c = tid + (i << 8);
      async16(&A[(size_t)(c >> 2) * K + k0 + ((c & 3) << 3)], &lA[(size_t)c << 3]);
      async16(&Bg[(size_t)(c >> 2) * K + k0 + ((c & 3) << 3)], &lB[(size_t)c << 3]);
    }
    __syncthreads();
    short8 af[4], bfr[4];
    #pragma unroll
    for (int i = 0; i < 4; i++) {
      af[i]  = *(const short8*)&lA[(wm + (i << 4) + l15) * 32 + (quad << 3)];
      bfr[i] = *(const short8*)&lB[(wn + (i << 4) + l15) * 32 + (quad << 3)];
    }
    #pragma unroll
    for (int mi = 0; mi < 4; mi++)
      #pragma unroll
      for (int ni = 0; ni < 4; ni++)
        acc[mi][ni] = __builtin_amdgcn_mfma_f32_16x16x32_bf16(af[mi], bfr[ni], acc[mi][ni], 0, 0, 0);
    __syncthreads();
  }

  #pragma unroll
  for (int mi = 0; mi < 4; mi++) {
    #pragma unroll
    for (int r = 0; r < 4; r++) {
      int rg = (blockIdx.y << 7) + wm + (mi << 4) + (quad << 2) + r;
      #pragma unroll
      for (int ni = 0; ni < 4; ni++) {
        int col = (bx << 7) + wn + (ni << 4) + l15;
        float t = acc[mi][ni][r] + bias[col];
        float act;
        if (isx) {
          float u = 0.7978845608028654f * (t + 0.044715f * t * t * t);
          float e = __expf(2.f * u);
          act = 0.5f * t * (1.f + (1.f - 2.f / (e + 1.f)));
        } else {
          act = t / (1.f + __expf(-t));
        }
        h1[(size_t)rg * 4096 + col] = f2bf(act);
      }
    }
  }
}

// ---------------- MLP layer 2: MT=64, full K, single writer (no atomics) --------
__global__ __launch_bounds__(256)
void mlp2(const u16* __restrict__ h1,
          const u16* __restrict__ Bx, const u16* __restrict__ Bc,
          const float* __restrict__ biasx, const float* __restrict__ biasc,
          const float* __restrict__ mvec, const float* __restrict__ ba,
          float* __restrict__ outx, float* __restrict__ outc) {
  bool isx = (blockIdx.y < 64);
  const u16* A = h1 + (size_t)(blockIdx.y << 6) * 4096;
  const u16* Bt = isx ? Bx : Bc;
  const float* bias = isx ? biasx : biasc;
  const int K = 4096;
  __shared__ alignas(16) u16 lA[64 * 32];
  __shared__ alignas(16) u16 lB[128 * 32];
  int tid = threadIdx.x;
  int wave = tid >> 6, lane = tid & 63, quad = lane >> 4, l15 = lane & 15;
  int bx = blockIdx.x;
  int wm = (wave >> 1) << 5, wn = (wave & 1) << 6;
  const u16* Bg = Bt + (size_t)(bx << 7) * K;
  floatx4 acc[2][4];
  #pragma unroll
  for (int i = 0; i < 2; i++)
    #pragma unroll
    for (int j = 0; j < 4; j++) acc[i][j] = zero4();

  for (int k0 = 0; k0 < K; k0 += 32) {
    {
      int c = tid;
      async16(&A[(size_t)(c >> 2) * K + k0 + ((c & 3) << 3)], &lA[(size_t)c << 3]);
    }
    #pragma unroll
    for (int i = 0; i < 2; i++) {
      int c = tid + (i << 8);
      async16(&Bg[(size_t)(c >> 2) * K + k0 + ((c & 3) << 3)], &lB[(size_t)c << 3]);
    }
    __syncthreads();
    short8 af[2], bfr[4];
    #pragma unroll
    for (int i = 0; i < 2; i++)
      af[i] = *(const short8*)&lA[(wm + (i << 4) + l15) * 32 + (quad << 3)];
    #pragma unroll
    for (int i = 0; i < 4; i++)
      bfr[i] = *(const short8*)&lB[(wn + (i << 4) + l15) * 32 + (quad << 3)];
    #pragma unroll
    for (int mi = 0; mi < 2; mi++)
      #pragma unroll
      for (int ni = 0; ni < 4; ni++)
        acc[mi][ni] = __builtin_amdgcn_mfma_f32_16x16x32_bf16(af[mi], bfr[ni], acc[mi][ni], 0, 0, 0);
    __syncthreads();
  }

  #pragma unroll
  for (int mi = 0; mi < 2; mi++) {
    #pragma unroll
    for (int r = 0; r < 4; r++) {
      int rg = (blockIdx.y << 6) + wm + (mi << 4) + (quad << 2) + r;
      int rl = isx ? rg : (rg - 4096);
      int b = isx ? (rg >> 11) : (rl >> 8);
      float* dst = isx ? outx : outc;
      #pragma unroll
      for (int ni = 0; ni < 4; ni++) {
        int col = (bx << 7) + wn + (ni << 4) + l15;
        float val = acc[mi][ni][r] + bias[col];
        float g = mvec[b * SIX_C + 5120 + col] + ba[5120 + col];
        size_t idx = (((size_t)rl) << 10) + col;
        dst[idx] = dst[idx] + val * g;
      }
    }
  }
}

// ---------------- flash attention (S^T trick; KV-split z=3; exp2 domain) -------
__global__ __launch_bounds__(256, 3)
void flash_attn(const u16* __restrict__ Q, const u16* __restrict__ K,
                const u16* __restrict__ V, u16* __restrict__ Op,
                float2* __restrict__ ml) {
  __shared__ alignas(16) u16 lK[128 * 64];
  __shared__ alignas(16) u16 lV[64 * 128];
  int tid = threadIdx.x;
  int wave = tid >> 6, lane = tid & 63, quad = lane >> 4, l15 = lane & 15;
  int q0 = blockIdx.x << 7;
  int bh = blockIdx.y;
  int z = blockIdx.z;
  const u16* Qb = Q + (size_t)bh * S_TOT * DH;
  const u16* Kb = K + (size_t)bh * S_TOT * DH;
  const u16* Vb = V + (size_t)bh * DH * S_TOT;

  // Q pre-scaled by 0.125*log2(e): scores exit QK^T in log2 domain
  short8 qf[2][2];
  #pragma unroll
  for (int mi = 0; mi < 2; mi++) {
    const u16* qrow = Qb + (size_t)(q0 + wave * 32 + mi * 16 + l15) * DH;
    #pragma unroll
    for (int kd = 0; kd < 2; kd++) {
      short8 raw = *(const short8*)&qrow[kd * 32 + quad * 8];
      short8 sc;
      #pragma unroll
      for (int j = 0; j < 8; j++) sc[j] = (short)f2bf(bf2f((u16)raw[j]) * 0.1803368801111244f);
      qf[mi][kd] = sc;
    }
  }

  floatx4 oacc[2][4];
  #pragma unroll
  for (int mi = 0; mi < 2; mi++)
    #pragma unroll
    for (int dt = 0; dt < 4; dt++) oacc[mi][dt] = zero4();
  float mst[2] = {-1e30f, -1e30f}, lst[2] = {0.f, 0.f};

  int kvbeg = z * 768, kvend = kvbeg + 768;
  for (int kv0 = kvbeg; kv0 < kvend; kv0 += 128) {
    #pragma unroll
    for (int i = 0; i < 4; i++) {
      int ci = tid + (i << 8);
      int rK = ci >> 3, clK = ci & 7;
      int cgK = clK ^ (rK & 7);
      async16(&Kb[(size_t)(kv0 + rK) * DH + (cgK << 3)], &lK[(size_t)ci << 3]);
      int rV = ci >> 4, clV = ci & 15;
      int cgV = (clV & 8) | ((clV ^ (rV & 7)) & 7);
      async16(&Vb[(size_t)rV * S_TOT + kv0 + (cgV << 3)], &lV[(size_t)ci << 3]);
    }
    __syncthreads();

    floatx4 sacc[2][8];
    #pragma unroll
    for (int mi = 0; mi < 2; mi++)
      #pragma unroll
      for (int si = 0; si < 8; si++) sacc[mi][si] = zero4();
    #pragma unroll
    for (int si = 0; si < 8; si++) {
      int r = si * 16 + l15;
      #pragma unroll
      for (int kd = 0; kd < 2; kd++) {
        int c = (kd << 2) + quad;
        int cl = c ^ (r & 7);
        short8 kf = *(const short8*)&lK[r * 64 + (cl << 3)];
        sacc[0][si] = __builtin_amdgcn_mfma_f32_16x16x32_bf16(kf, qf[0][kd], sacc[0][si], 0, 0, 0);
        sacc[1][si] = __builtin_amdgcn_mfma_f32_16x16x32_bf16(kf, qf[1][kd], sacc[1][si], 0, 0, 0);
      }
    }

    // online softmax (log2 domain) + immediate bf16 pack (sacc dies here)
    unsigned pu[2][8][2];
    #pragma unroll
    for (int mi = 0; mi < 2; mi++) {
      float rm = -1e30f;
      #pragma unroll
      for (int si = 0; si < 8; si++)
        #pragma unroll
        for (int r = 0; r < 4; r++) rm = fmaxf(rm, sacc[mi][si][r]);
      rm = fmaxf(rm, __shfl_xor(rm, 16));
      rm = fmaxf(rm, __shfl_xor(rm, 32));
      float mnew = fmaxf(mst[mi], rm);
      float al = fexp2(mst[mi] - mnew);
      mst[mi] = mnew;
      float rs = 0.f;
      #pragma unroll
      for (int si = 0; si < 8; si++) {
        float p0 = fexp2(sacc[mi][si][0] - mnew);
        float p1 = fexp2(sacc[mi][si][1] - mnew);
        float p2 = fexp2(sacc[mi][si][2] - mnew);
        float p3 = fexp2(sacc[mi][si][3] - mnew);
        rs += (p0 + p1) + (p2 + p3);
        pu[mi][si][0] = __builtin_amdgcn_perm(fbits(p1), fbits(p0), 0x07060302u);
        pu[mi][si][1] = __builtin_amdgcn_perm(fbits(p3), fbits(p2), 0x07060302u);
      }
      rs += __shfl_xor(rs, 16);
      rs += __shfl_xor(rs, 32);
      lst[mi] = lst[mi] * al + rs;
      #pragma unroll
      for (int dt = 0; dt < 4; dt++)
        #pragma unroll
        for (int r = 0; r < 4; r++) oacc[mi][dt][r] *= al;
    }

    #pragma unroll
    for (int si = 0; si < 8; si++) {
      union { s4b v; unsigned u[2]; } pb0, pb1;
      pb0.u[0] = pu[0][si][0]; pb0.u[1] = pu[0][si][1];
      pb1.u[0] = pu[1][si][0]; pb1.u[1] = pu[1][si][1];
      #pragma unroll
      for (int dt = 0; dt < 4; dt++) {
        int r = dt * 16 + l15;
        int c = (si << 1) + (quad >> 1);
        int cl = (c & 8) | ((c ^ (r & 7)) & 7);
        s4b vf = *(const s4b*)&lV[r * 128 + (cl << 3) + ((quad & 1) << 2)];
        oacc[0][dt] = __builtin_amdgcn_mfma_f32_16x16x16bf16_1k(vf, pb0.v, oacc[0][dt], 0, 0, 0);
        oacc[1][dt] = __builtin_amdgcn_mfma_f32_16x16x16bf16_1k(vf, pb1.v, oacc[1][dt], 0, 0, 0);
      }
    }
    __syncthreads();
  }

  u16* Ob = Op + (size_t)(z * 32 + bh) * S_TOT * DH;
  float2* mlb = ml + (size_t)(z * 32 + bh) * S_TOT;
  #pragma unroll
  for (int mi = 0; mi < 2; mi++) {
    int qg = q0 + wave * 32 + mi * 16 + l15;
    size_t base = (size_t)qg * DH;
    #pragma unroll
    for (int dt = 0; dt < 4; dt++) {
      s4b o;
      #pragma unroll
      for (int r = 0; r < 4; r++) o[r] = (short)f2bf(oacc[mi][dt][r]);
      *(s4b*)&Ob[base + dt * 16 + quad * 4] = o;
    }
    if (quad == 0) mlb[qg] = make_float2(mst[mi], lst[mi]);
  }
}

// ---------------- combine 3 KV-split partials (log2-domain m) ----------------
__global__ __launch_bounds__(256)
void attn_combine(const u16* __restrict__ Op, const float2* __restrict__ ml,
                  u16* __restrict__ O) {
  int tid = threadIdx.x;
  int row = blockIdx.x * 4 + (tid >> 6);
  int d = tid & 63;
  const size_t ZS = (size_t)32 * S_TOT;
  float2 a0 = ml[row], a1 = ml[ZS + row], a2 = ml[2 * ZS + row];
  float M = fmaxf(a0.x, fmaxf(a1.x, a2.x));
  float w0 = fexp2(a0.x - M), w1 = fexp2(a1.x - M), w2 = fexp2(a2.x - M);
  float L = w0 * a0.y + w1 * a1.y + w2 * a2.y;
  size_t stride = ZS * DH;
  size_t idx = (size_t)row * DH + d;
  float o = w0 * bf2f(Op[idx]) + w1 * bf2f(Op[stride + idx]) + w2 * bf2f(Op[2 * stride + idx]);
  o /= L;
  int bh = row / S_TOT, q = row - bh * S_TOT;
  int b = bh >> 4, h = bh & 15;
  O[(((size_t)(b * S_TOT + q)) << 10) + h * 64 + d] = f2bf(o);
}

// ---------------- launch ----------------
extern "C" void kernel_launch(void* const* d_in, const int* in_sizes, int n_in,
                              void* d_out, int out_size, void* d_ws, size_t ws_size,
                              hipStream_t stream) {
  const float* x       = (const float*)d_in[0];
  const float* mod     = (const float*)d_in[1];
  const float* cond    = (const float*)d_in[2];
  const float* w_adaln = (const float*)d_in[3];
  const float* b_adaln = (const float*)d_in[4];
  const float* w_qkv   = (const float*)d_in[5];
  const float* b_qkv   = (const float*)d_in[6];
  const float* w_proj  = (const float*)d_in[7];
  const float* b_proj  = (const float*)d_in[8];
  const float* w_s1    = (const float*)d_in[9];
  const float* b_s1    = (const float*)d_in[10];
  const float* w_s2    = (const float*)d_in[11];
  const float* b_s2    = (const float*)d_in[12];
  const float* w_d1    = (const float*)d_in[13];
  const float* b_d1    = (const float*)d_in[14];
  const float* w_d2    = (const float*)d_in[15];
  const float* b_d2    = (const float*)d_in[16];

  float* outx = (float*)d_out;
  float* outc = outx + (size_t)2 * N_SEQ * C_DIM;

  char* w = (char*)d_ws;
  auto alloc = [&](size_t bytes) { char* p = w; w += (bytes + 255) & ~(size_t)255; return p; };
  float* m_ws  = (float*)alloc(12288 * 4);
  u16* wqkvT   = (u16*)alloc((size_t)3072 * 1024 * 2);
  u16* wprojT  = (u16*)alloc((size_t)1024 * 1024 * 2);
  u16* ws1T    = (u16*)alloc((size_t)4096 * 1024 * 2);
  u16* ws2T    = (u16*)alloc((size_t)4096 * 1024 * 2);
  u16* wd1T    = (u16*)alloc((size_t)4096 * 1024 * 2);
  u16* wd2T    = (u16*)alloc((size_t)4096 * 1024 * 2);
  u16* joint   = (u16*)alloc((size_t)4608 * 1024 * 2);
  u16* Qb      = (u16*)alloc((size_t)4718592 * 2);
  u16* Kb      = (u16*)alloc((size_t)4718592 * 2);
  u16* Vb      = (u16*)alloc((size_t)4718592 * 2);
  u16* Vtb     = (u16*)alloc((size_t)4718592 * 2);
  u16* h1      = (u16*)alloc((size_t)4608 * 4096 * 2);
  u16* xln2 = Qb;
  u16* cln2 = Kb;
  u16* attn_out = joint;
  u16* O_part = h1;
  float2* ml = (float2*)(h1 + (size_t)3 * 32 * S_TOT * DH);

  size_t needed = (size_t)(w - (char*)d_ws);
  if (needed > ws_size) {
    hipMemsetAsync(d_out, 0, (size_t)out_size * 4, stream);
    return;
  }

  hipMemsetAsync(m_ws, 0, 12288 * 4, stream);
  adaln_mod<<<dim3(24, 2, 8), 256, 0, stream>>>(mod, w_adaln, m_ws);

  wtrans_all<<<20480, 256, 0, stream>>>(w_qkv, w_proj, w_s1, w_s2, w_d1, w_d2,
                                        wqkvT, wprojT, ws1T, ws2T, wd1T, wd2T);

  ln_mod<0><<<4608, 256, 0, stream>>>(x, cond, m_ws, b_adaln, nullptr, nullptr, joint);

  gemm_k<0, 128><<<dim3(24, 36), 256, 0, stream>>>(joint, wqkvT, b_qkv, 1024,
      nullptr, nullptr, nullptr, nullptr, nullptr, nullptr, Qb, Kb, Vb);

  vtrans<<<dim3(36, 32), 256, 0, stream>>>(Vb, Vtb);
  flash_attn<<<dim3(18, 32, 3), 256, 0, stream>>>(Qb, Kb, Vtb, O_part, ml);
  attn_combine<<<18432, 256, 0, stream>>>(O_part, ml, attn_out);

  gemm_k<1, 64><<<dim3(8, 72), 256, 0, stream>>>(attn_out, wprojT, b_proj, 1024,
      m_ws, b_adaln, x, cond, outx, outc, nullptr, nullptr, nullptr);

  ln_mod<3072><<<4608, 256, 0, stream>>>(outx, outc, m_ws, b_adaln, xln2, cln2, nullptr);

  mlp1<<<dim3(32, 36), 256, 0, stream>>>(xln2, cln2, ws1T, wd1T, b_s1, b_d1, h1);
  mlp2<<<dim3(8, 72), 256, 0, stream>>>(h1, ws2T, wd2T, b_s2, b_d2,
                                        m_ws, b_adaln, outx, outc);
}

// Round 6
// 523.312 us; speedup vs baseline: 1.1599x; 1.1599x over previous
//
#include <hip/hip_runtime.h>

typedef unsigned short u16;
typedef __attribute__((ext_vector_type(8))) short short8;
typedef __attribute__((ext_vector_type(4))) short s4b;
typedef __attribute__((ext_vector_type(4))) float floatx4;

#define S_TOT 2304
#define N_SEQ 2048
#define T_SEQ 256
#define C_DIM 1024
#define NH 16
#define DH 64
#define SIX_C 6144

__device__ __forceinline__ u16 f2bf(float f) {
  union { float f; unsigned u; } v; v.f = f;
  unsigned r = (v.u + 0x7FFFu + ((v.u >> 16) & 1u)) >> 16;
  return (u16)r;
}
__device__ __forceinline__ float bf2f(u16 u) {
  union { unsigned u; float f; } v; v.u = ((unsigned)u) << 16; return v.f;
}
__device__ __forceinline__ unsigned fbits(float f) {
  union { float f; unsigned u; } v; v.f = f; return v.u;
}
__device__ __forceinline__ float fexp2(float x) {
#if __has_builtin(__builtin_amdgcn_exp2f)
  return __builtin_amdgcn_exp2f(x);
#else
  return __expf(x * 0.6931471805599453f);
#endif
}

__device__ __forceinline__ void async16(const void* g, void* l) {
  __builtin_amdgcn_global_load_lds((const __attribute__((address_space(1))) void*)g,
                                   (__attribute__((address_space(3))) void*)l, 16, 0, 0);
}

__device__ __forceinline__ floatx4 zero4() {
  floatx4 z; z[0] = 0.f; z[1] = 0.f; z[2] = 0.f; z[3] = 0.f; return z;
}

// ---------------- adaLN modulation ----------------
__global__ __launch_bounds__(256)
void adaln_mod(const float* __restrict__ mod, const float* __restrict__ w,
               float* __restrict__ m) {
  __shared__ float sm[128];
  int b = blockIdx.y, kz = blockIdx.z;
  int tid = threadIdx.x;
  if (tid < 128) {
    float v = mod[b * C_DIM + kz * 128 + tid];
    sm[tid] = v / (1.f + __expf(-v));
  }
  __syncthreads();
  int j = blockIdx.x * 256 + tid;
  const float* wp = w + (size_t)(kz * 128) * SIX_C + j;
  float acc = 0.f;
  #pragma unroll 8
  for (int k = 0; k < 128; k++) acc += sm[k] * wp[(size_t)k * SIX_C];
  atomicAdd(&m[b * SIX_C + j], acc);
}

// ---------------- fused weight transpose + cast ----------------
__global__ __launch_bounds__(256)
void wtrans_all(const float* __restrict__ w0, const float* __restrict__ w1,
                const float* __restrict__ w2, const float* __restrict__ w3,
                const float* __restrict__ w4, const float* __restrict__ w5,
                u16* __restrict__ o0, u16* __restrict__ o1, u16* __restrict__ o2,
                u16* __restrict__ o3, u16* __restrict__ o4, u16* __restrict__ o5) {
  int bid = blockIdx.x;
  const float* W; u16* Wt; int K, N, bx, local;
  if (bid < 3072)       { W = w0; Wt = o0; K = 1024; N = 3072; bx = 96;  local = bid; }
  else if (bid < 4096)  { W = w1; Wt = o1; K = 1024; N = 1024; bx = 32;  local = bid - 3072; }
  else if (bid < 8192)  { W = w2; Wt = o2; K = 1024; N = 4096; bx = 128; local = bid - 4096; }
  else if (bid < 12288) { W = w3; Wt = o3; K = 4096; N = 1024; bx = 32;  local = bid - 8192; }
  else if (bid < 16384) { W = w4; Wt = o4; K = 1024; N = 4096; bx = 128; local = bid - 12288; }
  else                  { W = w5; Wt = o5; K = 4096; N = 1024; bx = 32;  local = bid - 16384; }
  int n0 = (local % bx) << 5, k0 = (local / bx) << 5;
  __shared__ float t[32][33];
  int tx = threadIdx.x & 31, ty = threadIdx.x >> 5;
  #pragma unroll
  for (int i = 0; i < 32; i += 8)
    t[ty + i][tx] = W[(size_t)(k0 + ty + i) * N + n0 + tx];
  __syncthreads();
  #pragma unroll
  for (int i = 0; i < 32; i += 8)
    Wt[(size_t)(n0 + ty + i) * K + k0 + tx] = f2bf(t[tx][ty + i]);
}

// ---------------- V[b,h,s,d] bf16 -> Vt[b,h,d,s] bf16 ----------------
__global__ __launch_bounds__(256)
void vtrans(const u16* __restrict__ V, u16* __restrict__ Vt) {
  __shared__ u16 t[64][65];
  int s0 = blockIdx.x << 6;
  int bh = blockIdx.y;
  const u16* src = V + (size_t)bh * S_TOT * DH;
  u16* dst = Vt + (size_t)bh * DH * S_TOT;
  int tid = threadIdx.x;
  #pragma unroll
  for (int i = 0; i < 16; i++) {
    int idx = tid + i * 256; int r = idx >> 6, c = idx & 63;
    t[r][c] = src[(size_t)(s0 + r) * DH + c];
  }
  __syncthreads();
  #pragma unroll
  for (int i = 0; i < 16; i++) {
    int idx = tid + i * 256; int r = idx >> 6, c = idx & 63;
    dst[(size_t)r * S_TOT + s0 + c] = t[c][r];
  }
}

// ---------------- LN + modulation -> bf16 ----------------
template<int SHIFT_OFS>
__global__ __launch_bounds__(256)
void ln_mod(const float* __restrict__ xin, const float* __restrict__ cin,
            const float* __restrict__ m, const float* __restrict__ ba,
            u16* __restrict__ xo, u16* __restrict__ co, u16* __restrict__ joint) {
  int row = blockIdx.x;
  int b = row / S_TOT, s = row - b * S_TOT;
  bool isx = (s < N_SEQ);
  size_t roff = isx ? (((size_t)(b * N_SEQ + s)) << 10)
                    : (((size_t)(b * T_SEQ + (s - N_SEQ))) << 10);
  const float* src = isx ? (xin + roff) : (cin + roff);
  int tid = threadIdx.x;
  float4 v = ((const float4*)src)[tid];
  float s1 = v.x + v.y + v.z + v.w;
  float s2 = v.x * v.x + v.y * v.y + v.z * v.z + v.w * v.w;
  #pragma unroll
  for (int o = 32; o; o >>= 1) { s1 += __shfl_xor(s1, o); s2 += __shfl_xor(s2, o); }
  __shared__ float red[8];
  int wv = tid >> 6, ln = tid & 63;
  if (ln == 0) { red[wv] = s1; red[4 + wv] = s2; }
  __syncthreads();
  s1 = red[0] + red[1] + red[2] + red[3];
  s2 = red[4] + red[5] + red[6] + red[7];
  float mu = s1 * (1.f / 1024.f);
  float var = s2 * (1.f / 1024.f) - mu * mu;
  float rstd = rsqrtf(var + 1e-6f);
  int c = tid << 2;
  const float* mb = m + b * SIX_C;
  float4 sc = *(const float4*)(mb + SHIFT_OFS + 1024 + c);
  float4 sb = *(const float4*)(ba + SHIFT_OFS + 1024 + c);
  float4 sh = *(const float4*)(mb + SHIFT_OFS + c);
  float4 hb = *(const float4*)(ba + SHIFT_OFS + c);
  float y0 = (v.x - mu) * rstd * (1.f + sc.x + sb.x) + sh.x + hb.x;
  float y1 = (v.y - mu) * rstd * (1.f + sc.y + sb.y) + sh.y + hb.y;
  float y2 = (v.z - mu) * rstd * (1.f + sc.z + sb.z) + sh.z + hb.z;
  float y3 = (v.w - mu) * rstd * (1.f + sc.w + sb.w) + sh.w + hb.w;
  unsigned long long o = (unsigned long long)f2bf(y0)
      | ((unsigned long long)f2bf(y1) << 16)
      | ((unsigned long long)f2bf(y2) << 32)
      | ((unsigned long long)f2bf(y3) << 48);
  u16* dst;
  if (SHIFT_OFS == 0) dst = joint + (((size_t)row) << 10);
  else dst = (isx ? xo : co) + roff;
  *(unsigned long long*)(dst + c) = o;
}

// ---------------- GEMM: MODE 0: qkv scatter, MODE 1: proj+res+gate ----------------
template<int MODE, int MT>
__global__ __launch_bounds__(256)
void gemm_k(const u16* __restrict__ A, const u16* __restrict__ Bt,
            const float* __restrict__ bias, int K,
            const float* __restrict__ mvec, const float* __restrict__ ba,
            const float* __restrict__ rx, const float* __restrict__ rc,
            float* __restrict__ ox, float* __restrict__ oc,
            u16* __restrict__ oq, u16* __restrict__ okd, u16* __restrict__ ov)
{
  __shared__ alignas(16) u16 lA[MT * 32];
  __shared__ alignas(16) u16 lB[128 * 32];
  int tid = threadIdx.x;
  int wave = tid >> 6, lane = tid & 63, quad = lane >> 4, l15 = lane & 15;
  int bx = blockIdx.x, by = blockIdx.y;
  const int MF = MT / 32;
  int wm = (wave >> 1) * (MT / 2), wn = (wave & 1) << 6;
  const u16* Ag = A + (size_t)(by * MT) * K;
  const u16* Bg = Bt + (size_t)(bx << 7) * K;
  floatx4 acc[MF][4];
  #pragma unroll
  for (int i = 0; i < MF; i++)
    #pragma unroll
    for (int j = 0; j < 4; j++) acc[i][j] = zero4();

  for (int k0 = 0; k0 < K; k0 += 32) {
    #pragma unroll
    for (int i = 0; i < MT / 64; i++) {
      int c = tid + (i << 8);
      async16(&Ag[(size_t)(c >> 2) * K + k0 + ((c & 3) << 3)], &lA[(size_t)c << 3]);
    }
    #pragma unroll
    for (int i = 0; i < 2; i++) {
      int c = tid + (i << 8);
      async16(&Bg[(size_t)(c >> 2) * K + k0 + ((c & 3) << 3)], &lB[(size_t)c << 3]);
    }
    __syncthreads();
    short8 af[MF], bfr[4];
    #pragma unroll
    for (int i = 0; i < MF; i++)
      af[i] = *(const short8*)&lA[(wm + (i << 4) + l15) * 32 + (quad << 3)];
    #pragma unroll
    for (int i = 0; i < 4; i++)
      bfr[i] = *(const short8*)&lB[(wn + (i << 4) + l15) * 32 + (quad << 3)];
    #pragma unroll
    for (int mi = 0; mi < MF; mi++)
      #pragma unroll
      for (int ni = 0; ni < 4; ni++)
        acc[mi][ni] = __builtin_amdgcn_mfma_f32_16x16x32_bf16(af[mi], bfr[ni], acc[mi][ni], 0, 0, 0);
    __syncthreads();
  }

  #pragma unroll
  for (int mi = 0; mi < MF; mi++) {
    #pragma unroll
    for (int r = 0; r < 4; r++) {
      int rg = by * MT + wm + (mi << 4) + (quad << 2) + r;
      int b = rg / S_TOT; int s = rg - b * S_TOT;
      if (MODE == 0) {
        #pragma unroll
        for (int ni = 0; ni < 4; ni++) {
          int col = (bx << 7) + wn + (ni << 4) + l15;
          float val = acc[mi][ni][r] + bias[col];
          int part = col >> 10, h = (col >> 6) & 15, d = col & 63;
          u16* dst = (part == 0) ? oq : (part == 1 ? okd : ov);
          dst[(((size_t)(b * NH + h)) * S_TOT + s) * DH + d] = f2bf(val);
        }
      } else {
        #pragma unroll
        for (int ni = 0; ni < 4; ni++) {
          int col = (bx << 7) + wn + (ni << 4) + l15;
          float val = acc[mi][ni][r] + bias[col];
          float g = mvec[b * SIX_C + 2048 + col] + ba[2048 + col];
          if (s < N_SEQ) {
            size_t idx = (((size_t)(b * N_SEQ + s)) << 10) + col;
            ox[idx] = rx[idx] + val * g;
          } else {
            size_t idx = (((size_t)(b * T_SEQ + (s - N_SEQ))) << 10) + col;
            oc[idx] = rc[idx] + val * g;
          }
        }
      }
    }
  }
}

// ---------------- fused MLP layer 1 ----------
__global__ __launch_bounds__(256)
void mlp1(const u16* __restrict__ Ax, const u16* __restrict__ Ac,
          const u16* __restrict__ Bx, const u16* __restrict__ Bc,
          const float* __restrict__ biasx, const float* __restrict__ biasc,
          u16* __restrict__ h1) {
  bool isx = (blockIdx.y < 32);
  const u16* A = isx ? (Ax + (size_t)(blockIdx.y << 7) * 1024)
                     : (Ac + (size_t)((blockIdx.y - 32) << 7) * 1024);
  const u16* Bt = isx ? Bx : Bc;
  const float* bias = isx ? biasx : biasc;
  const int K = 1024;
  __shared__ alignas(16) u16 lA[128 * 32];
  __shared__ alignas(16) u16 lB[128 * 32];
  int tid = threadIdx.x;
  int wave = tid >> 6, lane = tid & 63, quad = lane >> 4, l15 = lane & 15;
  int bx = blockIdx.x;
  int wm = (wave >> 1) << 6, wn = (wave & 1) << 6;
  const u16* Bg = Bt + (size_t)(bx << 7) * K;
  floatx4 acc[4][4];
  #pragma unroll
  for (int i = 0; i < 4; i++)
    #pragma unroll
    for (int j = 0; j < 4; j++) acc[i][j] = zero4();

  for (int k0 = 0; k0 < K; k0 += 32) {
    #pragma unroll
    for (int i = 0; i < 2; i++) {
      int c = tid + (i << 8);
      async16(&A[(size_t)(c >> 2) * K + k0 + ((c & 3) << 3)], &lA[(size_t)c << 3]);
      async16(&Bg[(size_t)(c >> 2) * K + k0 + ((c & 3) << 3)], &lB[(size_t)c << 3]);
    }
    __syncthreads();
    short8 af[4], bfr[4];
    #pragma unroll
    for (int i = 0; i < 4; i++) {
      af[i]  = *(const short8*)&lA[(wm + (i << 4) + l15) * 32 + (quad << 3)];
      bfr[i] = *(const short8*)&lB[(wn + (i << 4) + l15) * 32 + (quad << 3)];
    }
    #pragma unroll
    for (int mi = 0; mi < 4; mi++)
      #pragma unroll
      for (int ni = 0; ni < 4; ni++)
        acc[mi][ni] = __builtin_amdgcn_mfma_f32_16x16x32_bf16(af[mi], bfr[ni], acc[mi][ni], 0, 0, 0);
    __syncthreads();
  }

  #pragma unroll
  for (int mi = 0; mi < 4; mi++) {
    #pragma unroll
    for (int r = 0; r < 4; r++) {
      int rg = (blockIdx.y << 7) + wm + (mi << 4) + (quad << 2) + r;
      #pragma unroll
      for (int ni = 0; ni < 4; ni++) {
        int col = (bx << 7) + wn + (ni << 4) + l15;
        float t = acc[mi][ni][r] + bias[col];
        float act;
        if (isx) {
          float u = 0.7978845608028654f * (t + 0.044715f * t * t * t);
          float e = __expf(2.f * u);
          act = 0.5f * t * (1.f + (1.f - 2.f / (e + 1.f)));
        } else {
          act = t / (1.f + __expf(-t));
        }
        h1[(size_t)rg * 4096 + col] = f2bf(act);
      }
    }
  }
}

// ---------------- MLP layer 2: MT=64, full K, single writer --------
__global__ __launch_bounds__(256)
void mlp2(const u16* __restrict__ h1,
          const u16* __restrict__ Bx, const u16* __restrict__ Bc,
          const float* __restrict__ biasx, const float* __restrict__ biasc,
          const float* __restrict__ mvec, const float* __restrict__ ba,
          float* __restrict__ outx, float* __restrict__ outc) {
  bool isx = (blockIdx.y < 64);
  const u16* A = h1 + (size_t)(blockIdx.y << 6) * 4096;
  const u16* Bt = isx ? Bx : Bc;
  const float* bias = isx ? biasx : biasc;
  const int K = 4096;
  __shared__ alignas(16) u16 lA[64 * 32];
  __shared__ alignas(16) u16 lB[128 * 32];
  int tid = threadIdx.x;
  int wave = tid >> 6, lane = tid & 63, quad = lane >> 4, l15 = lane & 15;
  int bx = blockIdx.x;
  int wm = (wave >> 1) << 5, wn = (wave & 1) << 6;
  const u16* Bg = Bt + (size_t)(bx << 7) * K;
  floatx4 acc[2][4];
  #pragma unroll
  for (int i = 0; i < 2; i++)
    #pragma unroll
    for (int j = 0; j < 4; j++) acc[i][j] = zero4();

  for (int k0 = 0; k0 < K; k0 += 32) {
    {
      int c = tid;
      async16(&A[(size_t)(c >> 2) * K + k0 + ((c & 3) << 3)], &lA[(size_t)c << 3]);
    }
    #pragma unroll
    for (int i = 0; i < 2; i++) {
      int c = tid + (i << 8);
      async16(&Bg[(size_t)(c >> 2) * K + k0 + ((c & 3) << 3)], &lB[(size_t)c << 3]);
    }
    __syncthreads();
    short8 af[2], bfr[4];
    #pragma unroll
    for (int i = 0; i < 2; i++)
      af[i] = *(const short8*)&lA[(wm + (i << 4) + l15) * 32 + (quad << 3)];
    #pragma unroll
    for (int i = 0; i < 4; i++)
      bfr[i] = *(const short8*)&lB[(wn + (i << 4) + l15) * 32 + (quad << 3)];
    #pragma unroll
    for (int mi = 0; mi < 2; mi++)
      #pragma unroll
      for (int ni = 0; ni < 4; ni++)
        acc[mi][ni] = __builtin_amdgcn_mfma_f32_16x16x32_bf16(af[mi], bfr[ni], acc[mi][ni], 0, 0, 0);
    __syncthreads();
  }

  #pragma unroll
  for (int mi = 0; mi < 2; mi++) {
    #pragma unroll
    for (int r = 0; r < 4; r++) {
      int rg = (blockIdx.y << 6) + wm + (mi << 4) + (quad << 2) + r;
      int rl = isx ? rg : (rg - 4096);
      int b = isx ? (rg >> 11) : (rl >> 8);
      float* dst = isx ? outx : outc;
      #pragma unroll
      for (int ni = 0; ni < 4; ni++) {
        int col = (bx << 7) + wn + (ni << 4) + l15;
        float val = acc[mi][ni][r] + bias[col];
        float g = mvec[b * SIX_C + 5120 + col] + ba[5120 + col];
        size_t idx = (((size_t)rl) << 10) + col;
        dst[idx] = dst[idx] + val * g;
      }
    }
  }
}

// ---------------- flash attention (round-4 register structure + exp2 softmax) -------
__global__ __launch_bounds__(256)
void flash_attn(const u16* __restrict__ Q, const u16* __restrict__ K,
                const u16* __restrict__ V, u16* __restrict__ Op,
                float2* __restrict__ ml) {
  __shared__ alignas(16) u16 lK[128 * 64];
  __shared__ alignas(16) u16 lV[64 * 128];
  int tid = threadIdx.x;
  int wave = tid >> 6, lane = tid & 63, quad = lane >> 4, l15 = lane & 15;
  int q0 = blockIdx.x << 7;
  int bh = blockIdx.y;
  int z = blockIdx.z;
  const u16* Qb = Q + (size_t)bh * S_TOT * DH;
  const u16* Kb = K + (size_t)bh * S_TOT * DH;
  const u16* Vb = V + (size_t)bh * DH * S_TOT;

  // Q pre-scaled by 0.125*log2(e): scores exit QK^T in log2 domain
  short8 qf[2][2];
  #pragma unroll
  for (int mi = 0; mi < 2; mi++) {
    const u16* qrow = Qb + (size_t)(q0 + wave * 32 + mi * 16 + l15) * DH;
    #pragma unroll
    for (int kd = 0; kd < 2; kd++) {
      short8 raw = *(const short8*)&qrow[kd * 32 + quad * 8];
      short8 sc;
      #pragma unroll
      for (int j = 0; j < 8; j++) sc[j] = (short)f2bf(bf2f((u16)raw[j]) * 0.1803368801111244f);
      qf[mi][kd] = sc;
    }
  }

  floatx4 oacc[2][4];
  #pragma unroll
  for (int mi = 0; mi < 2; mi++)
    #pragma unroll
    for (int dt = 0; dt < 4; dt++) oacc[mi][dt] = zero4();
  float mst[2] = {-1e30f, -1e30f}, lst[2] = {0.f, 0.f};

  int kvbeg = z * 768, kvend = kvbeg + 768;
  for (int kv0 = kvbeg; kv0 < kvend; kv0 += 128) {
    #pragma unroll
    for (int i = 0; i < 4; i++) {
      int ci = tid + (i << 8);
      int rK = ci >> 3, clK = ci & 7;
      int cgK = clK ^ (rK & 7);
      async16(&Kb[(size_t)(kv0 + rK) * DH + (cgK << 3)], &lK[(size_t)ci << 3]);
      int rV = ci >> 4, clV = ci & 15;
      int cgV = (clV & 8) | ((clV ^ (rV & 7)) & 7);
      async16(&Vb[(size_t)rV * S_TOT + kv0 + (cgV << 3)], &lV[(size_t)ci << 3]);
    }
    __syncthreads();

    floatx4 sacc[2][8];
    #pragma unroll
    for (int mi = 0; mi < 2; mi++)
      #pragma unroll
      for (int si = 0; si < 8; si++) sacc[mi][si] = zero4();
    #pragma unroll
    for (int si = 0; si < 8; si++) {
      int r = si * 16 + l15;
      #pragma unroll
      for (int kd = 0; kd < 2; kd++) {
        int c = (kd << 2) + quad;
        int cl = c ^ (r & 7);
        short8 kf = *(const short8*)&lK[r * 64 + (cl << 3)];
        sacc[0][si] = __builtin_amdgcn_mfma_f32_16x16x32_bf16(kf, qf[0][kd], sacc[0][si], 0, 0, 0);
        sacc[1][si] = __builtin_amdgcn_mfma_f32_16x16x32_bf16(kf, qf[1][kd], sacc[1][si], 0, 0, 0);
      }
    }

    // online softmax in log2 domain; p written back into sacc
    #pragma unroll
    for (int mi = 0; mi < 2; mi++) {
      float rm = -1e30f;
      #pragma unroll
      for (int si = 0; si < 8; si++)
        #pragma unroll
        for (int r = 0; r < 4; r++) rm = fmaxf(rm, sacc[mi][si][r]);
      rm = fmaxf(rm, __shfl_xor(rm, 16));
      rm = fmaxf(rm, __shfl_xor(rm, 32));
      float mnew = fmaxf(mst[mi], rm);
      float al = fexp2(mst[mi] - mnew);
      mst[mi] = mnew;
      float rs = 0.f;
      #pragma unroll
      for (int si = 0; si < 8; si++)
        #pragma unroll
        for (int r = 0; r < 4; r++) {
          float p = fexp2(sacc[mi][si][r] - mnew);
          sacc[mi][si][r] = p;
          rs += p;
        }
      rs += __shfl_xor(rs, 16);
      rs += __shfl_xor(rs, 32);
      lst[mi] = lst[mi] * al + rs;
      #pragma unroll
      for (int dt = 0; dt < 4; dt++)
        #pragma unroll
        for (int r = 0; r < 4; r++) oacc[mi][dt][r] *= al;
    }

    // PV: pack P from sacc lane-locally (v_perm truncation) and feed as B operand
    #pragma unroll
    for (int si = 0; si < 8; si++) {
      s4b pb[2];
      #pragma unroll
      for (int mi = 0; mi < 2; mi++) {
        union { s4b v; unsigned u[2]; } p;
        p.u[0] = __builtin_amdgcn_perm(fbits(sacc[mi][si][1]), fbits(sacc[mi][si][0]), 0x07060302u);
        p.u[1] = __builtin_amdgcn_perm(fbits(sacc[mi][si][3]), fbits(sacc[mi][si][2]), 0x07060302u);
        pb[mi] = p.v;
      }
      #pragma unroll
      for (int dt = 0; dt < 4; dt++) {
        int r = dt * 16 + l15;
        int c = (si << 1) + (quad >> 1);
        int cl = (c & 8) | ((c ^ (r & 7)) & 7);
        s4b vf = *(const s4b*)&lV[r * 128 + (cl << 3) + ((quad & 1) << 2)];
        oacc[0][dt] = __builtin_amdgcn_mfma_f32_16x16x16bf16_1k(vf, pb[0], oacc[0][dt], 0, 0, 0);
        oacc[1][dt] = __builtin_amdgcn_mfma_f32_16x16x16bf16_1k(vf, pb[1], oacc[1][dt], 0, 0, 0);
      }
    }
    __syncthreads();
  }

  u16* Ob = Op + (size_t)(z * 32 + bh) * S_TOT * DH;
  float2* mlb = ml + (size_t)(z * 32 + bh) * S_TOT;
  #pragma unroll
  for (int mi = 0; mi < 2; mi++) {
    int qg = q0 + wave * 32 + mi * 16 + l15;
    size_t base = (size_t)qg * DH;
    #pragma unroll
    for (int dt = 0; dt < 4; dt++) {
      s4b o;
      #pragma unroll
      for (int r = 0; r < 4; r++) o[r] = (short)f2bf(oacc[mi][dt][r]);
      *(s4b*)&Ob[base + dt * 16 + quad * 4] = o;
    }
    if (quad == 0) mlb[qg] = make_float2(mst[mi], lst[mi]);
  }
}

// ---------------- combine 3 KV-split partials (log2-domain m) ----------------
__global__ __launch_bounds__(256)
void attn_combine(const u16* __restrict__ Op, const float2* __restrict__ ml,
                  u16* __restrict__ O) {
  int tid = threadIdx.x;
  int row = blockIdx.x * 4 + (tid >> 6);
  int d = tid & 63;
  const size_t ZS = (size_t)32 * S_TOT;
  float2 a0 = ml[row], a1 = ml[ZS + row], a2 = ml[2 * ZS + row];
  float M = fmaxf(a0.x, fmaxf(a1.x, a2.x));
  float w0 = fexp2(a0.x - M), w1 = fexp2(a1.x - M), w2 = fexp2(a2.x - M);
  float L = w0 * a0.y + w1 * a1.y + w2 * a2.y;
  size_t stride = ZS * DH;
  size_t idx = (size_t)row * DH + d;
  float o = w0 * bf2f(Op[idx]) + w1 * bf2f(Op[stride + idx]) + w2 * bf2f(Op[2 * stride + idx]);
  o /= L;
  int bh = row / S_TOT, q = row - bh * S_TOT;
  int b = bh >> 4, h = bh & 15;
  O[(((size_t)(b * S_TOT + q)) << 10) + h * 64 + d] = f2bf(o);
}

// ---------------- launch ----------------
extern "C" void kernel_launch(void* const* d_in, const int* in_sizes, int n_in,
                              void* d_out, int out_size, void* d_ws, size_t ws_size,
                              hipStream_t stream) {
  const float* x       = (const float*)d_in[0];
  const float* mod     = (const float*)d_in[1];
  const float* cond    = (const float*)d_in[2];
  const float* w_adaln = (const float*)d_in[3];
  const float* b_adaln = (const float*)d_in[4];
  const float* w_qkv   = (const float*)d_in[5];
  const float* b_qkv   = (const float*)d_in[6];
  const float* w_proj  = (const float*)d_in[7];
  const float* b_proj  = (const float*)d_in[8];
  const float* w_s1    = (const float*)d_in[9];
  const float* b_s1    = (const float*)d_in[10];
  const float* w_s2    = (const float*)d_in[11];
  const float* b_s2    = (const float*)d_in[12];
  const float* w_d1    = (const float*)d_in[13];
  const float* b_d1    = (const float*)d_in[14];
  const float* w_d2    = (const float*)d_in[15];
  const float* b_d2    = (const float*)d_in[16];

  float* outx = (float*)d_out;
  float* outc = outx + (size_t)2 * N_SEQ * C_DIM;

  char* w = (char*)d_ws;
  auto alloc = [&](size_t bytes) { char* p = w; w += (bytes + 255) & ~(size_t)255; return p; };
  float* m_ws  = (float*)alloc(12288 * 4);
  u16* wqkvT   = (u16*)alloc((size_t)3072 * 1024 * 2);
  u16* wprojT  = (u16*)alloc((size_t)1024 * 1024 * 2);
  u16* ws1T    = (u16*)alloc((size_t)4096 * 1024 * 2);
  u16* ws2T    = (u16*)alloc((size_t)4096 * 1024 * 2);
  u16* wd1T    = (u16*)alloc((size_t)4096 * 1024 * 2);
  u16* wd2T    = (u16*)alloc((size_t)4096 * 1024 * 2);
  u16* joint   = (u16*)alloc((size_t)4608 * 1024 * 2);
  u16* Qb      = (u16*)alloc((size_t)4718592 * 2);
  u16* Kb      = (u16*)alloc((size_t)4718592 * 2);
  u16* Vb      = (u16*)alloc((size_t)4718592 * 2);
  u16* Vtb     = (u16*)alloc((size_t)4718592 * 2);
  u16* h1      = (u16*)alloc((size_t)4608 * 4096 * 2);
  u16* xln2 = Qb;
  u16* cln2 = Kb;
  u16* attn_out = joint;
  u16* O_part = h1;
  float2* ml = (float2*)(h1 + (size_t)3 * 32 * S_TOT * DH);

  size_t needed = (size_t)(w - (char*)d_ws);
  if (needed > ws_size) {
    hipMemsetAsync(d_out, 0, (size_t)out_size * 4, stream);
    return;
  }

  hipMemsetAsync(m_ws, 0, 12288 * 4, stream);
  adaln_mod<<<dim3(24, 2, 8), 256, 0, stream>>>(mod, w_adaln, m_ws);

  wtrans_all<<<20480, 256, 0, stream>>>(w_qkv, w_proj, w_s1, w_s2, w_d1, w_d2,
                                        wqkvT, wprojT, ws1T, ws2T, wd1T, wd2T);

  ln_mod<0><<<4608, 256, 0, stream>>>(x, cond, m_ws, b_adaln, nullptr, nullptr, joint);

  gemm_k<0, 128><<<dim3(24, 36), 256, 0, stream>>>(joint, wqkvT, b_qkv, 1024,
      nullptr, nullptr, nullptr, nullptr, nullptr, nullptr, Qb, Kb, Vb);

  vtrans<<<dim3(36, 32), 256, 0, stream>>>(Vb, Vtb);
  flash_attn<<<dim3(18, 32, 3), 256, 0, stream>>>(Qb, Kb, Vtb, O_part, ml);
  attn_combine<<<18432, 256, 0, stream>>>(O_part, ml, attn_out);

  gemm_k<1, 64><<<dim3(8, 72), 256, 0, stream>>>(attn_out, wprojT, b_proj, 1024,
      m_ws, b_adaln, x, cond, outx, outc, nullptr, nullptr, nullptr);

  ln_mod<3072><<<4608, 256, 0, stream>>>(outx, outc, m_ws, b_adaln, xln2, cln2, nullptr);

  mlp1<<<dim3(32, 36), 256, 0, stream>>>(xln2, cln2, ws1T, wd1T, b_s1, b_d1, h1);
  mlp2<<<dim3(8, 72), 256, 0, stream>>>(h1, ws2T, wd2T, b_s2, b_d2,
                                        m_ws, b_adaln, outx, outc);
}

// Round 7
// 503.903 us; speedup vs baseline: 1.2046x; 1.0385x over previous
//
#include <hip/hip_runtime.h>

typedef unsigned short u16;
typedef __attribute__((ext_vector_type(8))) short short8;
typedef __attribute__((ext_vector_type(4))) short s4b;
typedef __attribute__((ext_vector_type(4))) float floatx4;

#define S_TOT 2304
#define N_SEQ 2048
#define T_SEQ 256
#define C_DIM 1024
#define NH 16
#define DH 64
#define SIX_C 6144

__device__ __forceinline__ u16 f2bf(float f) {
  union { float f; unsigned u; } v; v.f = f;
  unsigned r = (v.u + 0x7FFFu + ((v.u >> 16) & 1u)) >> 16;
  return (u16)r;
}
__device__ __forceinline__ float bf2f(u16 u) {
  union { unsigned u; float f; } v; v.u = ((unsigned)u) << 16; return v.f;
}
__device__ __forceinline__ unsigned fbits(float f) {
  union { float f; unsigned u; } v; v.f = f; return v.u;
}
__device__ __forceinline__ float fexp2(float x) {
#if __has_builtin(__builtin_amdgcn_exp2f)
  return __builtin_amdgcn_exp2f(x);
#else
  return __expf(x * 0.6931471805599453f);
#endif
}

__device__ __forceinline__ void async16(const void* g, void* l) {
  __builtin_amdgcn_global_load_lds((const __attribute__((address_space(1))) void*)g,
                                   (__attribute__((address_space(3))) void*)l, 16, 0, 0);
}

__device__ __forceinline__ floatx4 zero4() {
  floatx4 z; z[0] = 0.f; z[1] = 0.f; z[2] = 0.f; z[3] = 0.f; return z;
}

// ---------------- adaLN modulation ----------------
__global__ __launch_bounds__(256)
void adaln_mod(const float* __restrict__ mod, const float* __restrict__ w,
               float* __restrict__ m) {
  __shared__ float sm[128];
  int b = blockIdx.y, kz = blockIdx.z;
  int tid = threadIdx.x;
  if (tid < 128) {
    float v = mod[b * C_DIM + kz * 128 + tid];
    sm[tid] = v / (1.f + __expf(-v));
  }
  __syncthreads();
  int j = blockIdx.x * 256 + tid;
  const float* wp = w + (size_t)(kz * 128) * SIX_C + j;
  float acc = 0.f;
  #pragma unroll 8
  for (int k = 0; k < 128; k++) acc += sm[k] * wp[(size_t)k * SIX_C];
  atomicAdd(&m[b * SIX_C + j], acc);
}

// ---------------- fused weight transpose + cast ----------------
__global__ __launch_bounds__(256)
void wtrans_all(const float* __restrict__ w0, const float* __restrict__ w1,
                const float* __restrict__ w2, const float* __restrict__ w3,
                const float* __restrict__ w4, const float* __restrict__ w5,
                u16* __restrict__ o0, u16* __restrict__ o1, u16* __restrict__ o2,
                u16* __restrict__ o3, u16* __restrict__ o4, u16* __restrict__ o5) {
  int bid = blockIdx.x;
  const float* W; u16* Wt; int K, N, bx, local;
  if (bid < 3072)       { W = w0; Wt = o0; K = 1024; N = 3072; bx = 96;  local = bid; }
  else if (bid < 4096)  { W = w1; Wt = o1; K = 1024; N = 1024; bx = 32;  local = bid - 3072; }
  else if (bid < 8192)  { W = w2; Wt = o2; K = 1024; N = 4096; bx = 128; local = bid - 4096; }
  else if (bid < 12288) { W = w3; Wt = o3; K = 4096; N = 1024; bx = 32;  local = bid - 8192; }
  else if (bid < 16384) { W = w4; Wt = o4; K = 1024; N = 4096; bx = 128; local = bid - 12288; }
  else                  { W = w5; Wt = o5; K = 4096; N = 1024; bx = 32;  local = bid - 16384; }
  int n0 = (local % bx) << 5, k0 = (local / bx) << 5;
  __shared__ float t[32][33];
  int tx = threadIdx.x & 31, ty = threadIdx.x >> 5;
  #pragma unroll
  for (int i = 0; i < 32; i += 8)
    t[ty + i][tx] = W[(size_t)(k0 + ty + i) * N + n0 + tx];
  __syncthreads();
  #pragma unroll
  for (int i = 0; i < 32; i += 8)
    Wt[(size_t)(n0 + ty + i) * K + k0 + tx] = f2bf(t[tx][ty + i]);
}

// ---------------- V[b,h,s,d] bf16 -> Vt[b,h,d,s] bf16 ----------------
__global__ __launch_bounds__(256)
void vtrans(const u16* __restrict__ V, u16* __restrict__ Vt) {
  __shared__ u16 t[64][65];
  int s0 = blockIdx.x << 6;
  int bh = blockIdx.y;
  const u16* src = V + (size_t)bh * S_TOT * DH;
  u16* dst = Vt + (size_t)bh * DH * S_TOT;
  int tid = threadIdx.x;
  #pragma unroll
  for (int i = 0; i < 16; i++) {
    int idx = tid + i * 256; int r = idx >> 6, c = idx & 63;
    t[r][c] = src[(size_t)(s0 + r) * DH + c];
  }
  __syncthreads();
  #pragma unroll
  for (int i = 0; i < 16; i++) {
    int idx = tid + i * 256; int r = idx >> 6, c = idx & 63;
    dst[(size_t)r * S_TOT + s0 + c] = t[c][r];
  }
}

// ---------------- LN + modulation -> bf16 ----------------
template<int SHIFT_OFS>
__global__ __launch_bounds__(256)
void ln_mod(const float* __restrict__ xin, const float* __restrict__ cin,
            const float* __restrict__ m, const float* __restrict__ ba,
            u16* __restrict__ xo, u16* __restrict__ co, u16* __restrict__ joint) {
  int row = blockIdx.x;
  int b = row / S_TOT, s = row - b * S_TOT;
  bool isx = (s < N_SEQ);
  size_t roff = isx ? (((size_t)(b * N_SEQ + s)) << 10)
                    : (((size_t)(b * T_SEQ + (s - N_SEQ))) << 10);
  const float* src = isx ? (xin + roff) : (cin + roff);
  int tid = threadIdx.x;
  float4 v = ((const float4*)src)[tid];
  float s1 = v.x + v.y + v.z + v.w;
  float s2 = v.x * v.x + v.y * v.y + v.z * v.z + v.w * v.w;
  #pragma unroll
  for (int o = 32; o; o >>= 1) { s1 += __shfl_xor(s1, o); s2 += __shfl_xor(s2, o); }
  __shared__ float red[8];
  int wv = tid >> 6, ln = tid & 63;
  if (ln == 0) { red[wv] = s1; red[4 + wv] = s2; }
  __syncthreads();
  s1 = red[0] + red[1] + red[2] + red[3];
  s2 = red[4] + red[5] + red[6] + red[7];
  float mu = s1 * (1.f / 1024.f);
  float var = s2 * (1.f / 1024.f) - mu * mu;
  float rstd = rsqrtf(var + 1e-6f);
  int c = tid << 2;
  const float* mb = m + b * SIX_C;
  float4 sc = *(const float4*)(mb + SHIFT_OFS + 1024 + c);
  float4 sb = *(const float4*)(ba + SHIFT_OFS + 1024 + c);
  float4 sh = *(const float4*)(mb + SHIFT_OFS + c);
  float4 hb = *(const float4*)(ba + SHIFT_OFS + c);
  float y0 = (v.x - mu) * rstd * (1.f + sc.x + sb.x) + sh.x + hb.x;
  float y1 = (v.y - mu) * rstd * (1.f + sc.y + sb.y) + sh.y + hb.y;
  float y2 = (v.z - mu) * rstd * (1.f + sc.z + sb.z) + sh.z + hb.z;
  float y3 = (v.w - mu) * rstd * (1.f + sc.w + sb.w) + sh.w + hb.w;
  unsigned long long o = (unsigned long long)f2bf(y0)
      | ((unsigned long long)f2bf(y1) << 16)
      | ((unsigned long long)f2bf(y2) << 32)
      | ((unsigned long long)f2bf(y3) << 48);
  u16* dst;
  if (SHIFT_OFS == 0) dst = joint + (((size_t)row) << 10);
  else dst = (isx ? xo : co) + roff;
  *(unsigned long long*)(dst + c) = o;
}

// ---------------- GEMM BK=64, source-XOR-swizzled staging -------------------
// MODE 0: qkv scatter, MODE 1: proj+res+gate. MT = 128 or 64.
template<int MODE, int MT>
__global__ __launch_bounds__(256)
void gemm_k(const u16* __restrict__ A, const u16* __restrict__ Bt,
            const float* __restrict__ bias, int K,
            const float* __restrict__ mvec, const float* __restrict__ ba,
            const float* __restrict__ rx, const float* __restrict__ rc,
            float* __restrict__ ox, float* __restrict__ oc,
            u16* __restrict__ oq, u16* __restrict__ okd, u16* __restrict__ ov)
{
  __shared__ alignas(16) u16 lA[MT * 64];
  __shared__ alignas(16) u16 lB[128 * 64];
  int tid = threadIdx.x;
  int wave = tid >> 6, lane = tid & 63, quad = lane >> 4, l15 = lane & 15;
  int bx = blockIdx.x, by = blockIdx.y;
  const int MF = MT / 32;
  const int ACH = MT / 32;              // A chunks per thread
  int wm = (wave >> 1) * (MT / 2), wn = (wave & 1) << 6;
  const u16* Ag = A + (size_t)(by * MT) * K;
  const u16* Bg = Bt + (size_t)(bx << 7) * K;
  floatx4 acc[MF][4];
  #pragma unroll
  for (int i = 0; i < MF; i++)
    #pragma unroll
    for (int j = 0; j < 4; j++) acc[i][j] = zero4();

  for (int k0 = 0; k0 < K; k0 += 64) {
    #pragma unroll
    for (int i = 0; i < ACH; i++) {
      int c = tid + (i << 8);
      int r = c >> 3, gc = (c & 7) ^ (r & 7);
      async16(&Ag[(size_t)r * K + k0 + (gc << 3)], &lA[(size_t)c << 3]);
    }
    #pragma unroll
    for (int i = 0; i < 4; i++) {
      int c = tid + (i << 8);
      int r = c >> 3, gc = (c & 7) ^ (r & 7);
      async16(&Bg[(size_t)r * K + k0 + (gc << 3)], &lB[(size_t)c << 3]);
    }
    __syncthreads();
    #pragma unroll
    for (int ks = 0; ks < 2; ks++) {
      short8 af[MF], bfr[4];
      #pragma unroll
      for (int i = 0; i < MF; i++) {
        int r = wm + (i << 4) + l15;
        af[i] = *(const short8*)&lA[r * 64 + ((((ks << 2) + quad) ^ (r & 7)) << 3)];
      }
      #pragma unroll
      for (int i = 0; i < 4; i++) {
        int r = wn + (i << 4) + l15;
        bfr[i] = *(const short8*)&lB[r * 64 + ((((ks << 2) + quad) ^ (r & 7)) << 3)];
      }
      #pragma unroll
      for (int mi = 0; mi < MF; mi++)
        #pragma unroll
        for (int ni = 0; ni < 4; ni++)
          acc[mi][ni] = __builtin_amdgcn_mfma_f32_16x16x32_bf16(af[mi], bfr[ni], acc[mi][ni], 0, 0, 0);
    }
    __syncthreads();
  }

  #pragma unroll
  for (int mi = 0; mi < MF; mi++) {
    #pragma unroll
    for (int r = 0; r < 4; r++) {
      int rg = by * MT + wm + (mi << 4) + (quad << 2) + r;
      int b = rg / S_TOT; int s = rg - b * S_TOT;
      if (MODE == 0) {
        #pragma unroll
        for (int ni = 0; ni < 4; ni++) {
          int col = (bx << 7) + wn + (ni << 4) + l15;
          float val = acc[mi][ni][r] + bias[col];
          int part = col >> 10, h = (col >> 6) & 15, d = col & 63;
          u16* dst = (part == 0) ? oq : (part == 1 ? okd : ov);
          dst[(((size_t)(b * NH + h)) * S_TOT + s) * DH + d] = f2bf(val);
        }
      } else {
        #pragma unroll
        for (int ni = 0; ni < 4; ni++) {
          int col = (bx << 7) + wn + (ni << 4) + l15;
          float val = acc[mi][ni][r] + bias[col];
          float g = mvec[b * SIX_C + 2048 + col] + ba[2048 + col];
          if (s < N_SEQ) {
            size_t idx = (((size_t)(b * N_SEQ + s)) << 10) + col;
            ox[idx] = rx[idx] + val * g;
          } else {
            size_t idx = (((size_t)(b * T_SEQ + (s - N_SEQ))) << 10) + col;
            oc[idx] = rc[idx] + val * g;
          }
        }
      }
    }
  }
}

// ---------------- fused MLP layer 1 (BK=64, swizzled) ----------
__global__ __launch_bounds__(256)
void mlp1(const u16* __restrict__ Ax, const u16* __restrict__ Ac,
          const u16* __restrict__ Bx, const u16* __restrict__ Bc,
          const float* __restrict__ biasx, const float* __restrict__ biasc,
          u16* __restrict__ h1) {
  bool isx = (blockIdx.y < 32);
  const u16* A = isx ? (Ax + (size_t)(blockIdx.y << 7) * 1024)
                     : (Ac + (size_t)((blockIdx.y - 32) << 7) * 1024);
  const u16* Bt = isx ? Bx : Bc;
  const float* bias = isx ? biasx : biasc;
  const int K = 1024;
  __shared__ alignas(16) u16 lA[128 * 64];
  __shared__ alignas(16) u16 lB[128 * 64];
  int tid = threadIdx.x;
  int wave = tid >> 6, lane = tid & 63, quad = lane >> 4, l15 = lane & 15;
  int bx = blockIdx.x;
  int wm = (wave >> 1) << 6, wn = (wave & 1) << 6;
  const u16* Bg = Bt + (size_t)(bx << 7) * K;
  floatx4 acc[4][4];
  #pragma unroll
  for (int i = 0; i < 4; i++)
    #pragma unroll
    for (int j = 0; j < 4; j++) acc[i][j] = zero4();

  for (int k0 = 0; k0 < K; k0 += 64) {
    #pragma unroll
    for (int i = 0; i < 4; i++) {
      int c = tid + (i << 8);
      int r = c >> 3, gc = (c & 7) ^ (r & 7);
      async16(&A[(size_t)r * K + k0 + (gc << 3)], &lA[(size_t)c << 3]);
      async16(&Bg[(size_t)r * K + k0 + (gc << 3)], &lB[(size_t)c << 3]);
    }
    __syncthreads();
    #pragma unroll
    for (int ks = 0; ks < 2; ks++) {
      short8 af[4], bfr[4];
      #pragma unroll
      for (int i = 0; i < 4; i++) {
        int ra = wm + (i << 4) + l15;
        af[i] = *(const short8*)&lA[ra * 64 + ((((ks << 2) + quad) ^ (ra & 7)) << 3)];
        int rb = wn + (i << 4) + l15;
        bfr[i] = *(const short8*)&lB[rb * 64 + ((((ks << 2) + quad) ^ (rb & 7)) << 3)];
      }
      #pragma unroll
      for (int mi = 0; mi < 4; mi++)
        #pragma unroll
        for (int ni = 0; ni < 4; ni++)
          acc[mi][ni] = __builtin_amdgcn_mfma_f32_16x16x32_bf16(af[mi], bfr[ni], acc[mi][ni], 0, 0, 0);
    }
    __syncthreads();
  }

  #pragma unroll
  for (int mi = 0; mi < 4; mi++) {
    #pragma unroll
    for (int r = 0; r < 4; r++) {
      int rg = (blockIdx.y << 7) + wm + (mi << 4) + (quad << 2) + r;
      #pragma unroll
      for (int ni = 0; ni < 4; ni++) {
        int col = (bx << 7) + wn + (ni << 4) + l15;
        float t = acc[mi][ni][r] + bias[col];
        float act;
        if (isx) {
          float u = 0.7978845608028654f * (t + 0.044715f * t * t * t);
          float e = __expf(2.f * u);
          act = 0.5f * t * (1.f + (1.f - 2.f / (e + 1.f)));
        } else {
          act = t / (1.f + __expf(-t));
        }
        h1[(size_t)rg * 4096 + col] = f2bf(act);
      }
    }
  }
}

// ---------------- MLP layer 2: MT=64, BK=64, full K, single writer --------
__global__ __launch_bounds__(256)
void mlp2(const u16* __restrict__ h1,
          const u16* __restrict__ Bx, const u16* __restrict__ Bc,
          const float* __restrict__ biasx, const float* __restrict__ biasc,
          const float* __restrict__ mvec, const float* __restrict__ ba,
          float* __restrict__ outx, float* __restrict__ outc) {
  bool isx = (blockIdx.y < 64);
  const u16* A = h1 + (size_t)(blockIdx.y << 6) * 4096;
  const u16* Bt = isx ? Bx : Bc;
  const float* bias = isx ? biasx : biasc;
  const int K = 4096;
  __shared__ alignas(16) u16 lA[64 * 64];
  __shared__ alignas(16) u16 lB[128 * 64];
  int tid = threadIdx.x;
  int wave = tid >> 6, lane = tid & 63, quad = lane >> 4, l15 = lane & 15;
  int bx = blockIdx.x;
  int wm = (wave >> 1) << 5, wn = (wave & 1) << 6;
  const u16* Bg = Bt + (size_t)(bx << 7) * K;
  floatx4 acc[2][4];
  #pragma unroll
  for (int i = 0; i < 2; i++)
    #pragma unroll
    for (int j = 0; j < 4; j++) acc[i][j] = zero4();

  for (int k0 = 0; k0 < K; k0 += 64) {
    #pragma unroll
    for (int i = 0; i < 2; i++) {
      int c = tid + (i << 8);
      int r = c >> 3, gc = (c & 7) ^ (r & 7);
      async16(&A[(size_t)r * K + k0 + (gc << 3)], &lA[(size_t)c << 3]);
    }
    #pragma unroll
    for (int i = 0; i < 4; i++) {
      int c = tid + (i << 8);
      int r = c >> 3, gc = (c & 7) ^ (r & 7);
      async16(&Bg[(size_t)r * K + k0 + (gc << 3)], &lB[(size_t)c << 3]);
    }
    __syncthreads();
    #pragma unroll
    for (int ks = 0; ks < 2; ks++) {
      short8 af[2], bfr[4];
      #pragma unroll
      for (int i = 0; i < 2; i++) {
        int r = wm + (i << 4) + l15;
        af[i] = *(const short8*)&lA[r * 64 + ((((ks << 2) + quad) ^ (r & 7)) << 3)];
      }
      #pragma unroll
      for (int i = 0; i < 4; i++) {
        int r = wn + (i << 4) + l15;
        bfr[i] = *(const short8*)&lB[r * 64 + ((((ks << 2) + quad) ^ (r & 7)) << 3)];
      }
      #pragma unroll
      for (int mi = 0; mi < 2; mi++)
        #pragma unroll
        for (int ni = 0; ni < 4; ni++)
          acc[mi][ni] = __builtin_amdgcn_mfma_f32_16x16x32_bf16(af[mi], bfr[ni], acc[mi][ni], 0, 0, 0);
    }
    __syncthreads();
  }

  #pragma unroll
  for (int mi = 0; mi < 2; mi++) {
    #pragma unroll
    for (int r = 0; r < 4; r++) {
      int rg = (blockIdx.y << 6) + wm + (mi << 4) + (quad << 2) + r;
      int rl = isx ? rg : (rg - 4096);
      int b = isx ? (rg >> 11) : (rl >> 8);
      float* dst = isx ? outx : outc;
      #pragma unroll
      for (int ni = 0; ni < 4; ni++) {
        int col = (bx << 7) + wn + (ni << 4) + l15;
        float val = acc[mi][ni][r] + bias[col];
        float g = mvec[b * SIX_C + 5120 + col] + ba[5120 + col];
        size_t idx = (((size_t)rl) << 10) + col;
        dst[idx] = dst[idx] + val * g;
      }
    }
  }
}

// ---------------- flash attention (round-6, unchanged) -------
__global__ __launch_bounds__(256)
void flash_attn(const u16* __restrict__ Q, const u16* __restrict__ K,
                const u16* __restrict__ V, u16* __restrict__ Op,
                float2* __restrict__ ml) {
  __shared__ alignas(16) u16 lK[128 * 64];
  __shared__ alignas(16) u16 lV[64 * 128];
  int tid = threadIdx.x;
  int wave = tid >> 6, lane = tid & 63, quad = lane >> 4, l15 = lane & 15;
  int q0 = blockIdx.x << 7;
  int bh = blockIdx.y;
  int z = blockIdx.z;
  const u16* Qb = Q + (size_t)bh * S_TOT * DH;
  const u16* Kb = K + (size_t)bh * S_TOT * DH;
  const u16* Vb = V + (size_t)bh * DH * S_TOT;

  short8 qf[2][2];
  #pragma unroll
  for (int mi = 0; mi < 2; mi++) {
    const u16* qrow = Qb + (size_t)(q0 + wave * 32 + mi * 16 + l15) * DH;
    #pragma unroll
    for (int kd = 0; kd < 2; kd++) {
      short8 raw = *(const short8*)&qrow[kd * 32 + quad * 8];
      short8 sc;
      #pragma unroll
      for (int j = 0; j < 8; j++) sc[j] = (short)f2bf(bf2f((u16)raw[j]) * 0.1803368801111244f);
      qf[mi][kd] = sc;
    }
  }

  floatx4 oacc[2][4];
  #pragma unroll
  for (int mi = 0; mi < 2; mi++)
    #pragma unroll
    for (int dt = 0; dt < 4; dt++) oacc[mi][dt] = zero4();
  float mst[2] = {-1e30f, -1e30f}, lst[2] = {0.f, 0.f};

  int kvbeg = z * 768, kvend = kvbeg + 768;
  for (int kv0 = kvbeg; kv0 < kvend; kv0 += 128) {
    #pragma unroll
    for (int i = 0; i < 4; i++) {
      int ci = tid + (i << 8);
      int rK = ci >> 3, clK = ci & 7;
      int cgK = clK ^ (rK & 7);
      async16(&Kb[(size_t)(kv0 + rK) * DH + (cgK << 3)], &lK[(size_t)ci << 3]);
      int rV = ci >> 4, clV = ci & 15;
      int cgV = (clV & 8) | ((clV ^ (rV & 7)) & 7);
      async16(&Vb[(size_t)rV * S_TOT + kv0 + (cgV << 3)], &lV[(size_t)ci << 3]);
    }
    __syncthreads();

    floatx4 sacc[2][8];
    #pragma unroll
    for (int mi = 0; mi < 2; mi++)
      #pragma unroll
      for (int si = 0; si < 8; si++) sacc[mi][si] = zero4();
    #pragma unroll
    for (int si = 0; si < 8; si++) {
      int r = si * 16 + l15;
      #pragma unroll
      for (int kd = 0; kd < 2; kd++) {
        int c = (kd << 2) + quad;
        int cl = c ^ (r & 7);
        short8 kf = *(const short8*)&lK[r * 64 + (cl << 3)];
        sacc[0][si] = __builtin_amdgcn_mfma_f32_16x16x32_bf16(kf, qf[0][kd], sacc[0][si], 0, 0, 0);
        sacc[1][si] = __builtin_amdgcn_mfma_f32_16x16x32_bf16(kf, qf[1][kd], sacc[1][si], 0, 0, 0);
      }
    }

    #pragma unroll
    for (int mi = 0; mi < 2; mi++) {
      float rm = -1e30f;
      #pragma unroll
      for (int si = 0; si < 8; si++)
        #pragma unroll
        for (int r = 0; r < 4; r++) rm = fmaxf(rm, sacc[mi][si][r]);
      rm = fmaxf(rm, __shfl_xor(rm, 16));
      rm = fmaxf(rm, __shfl_xor(rm, 32));
      float mnew = fmaxf(mst[mi], rm);
      float al = fexp2(mst[mi] - mnew);
      mst[mi] = mnew;
      float rs = 0.f;
      #pragma unroll
      for (int si = 0; si < 8; si++)
        #pragma unroll
        for (int r = 0; r < 4; r++) {
          float p = fexp2(sacc[mi][si][r] - mnew);
          sacc[mi][si][r] = p;
          rs += p;
        }
      rs += __shfl_xor(rs, 16);
      rs += __shfl_xor(rs, 32);
      lst[mi] = lst[mi] * al + rs;
      #pragma unroll
      for (int dt = 0; dt < 4; dt++)
        #pragma unroll
        for (int r = 0; r < 4; r++) oacc[mi][dt][r] *= al;
    }

    #pragma unroll
    for (int si = 0; si < 8; si++) {
      s4b pb[2];
      #pragma unroll
      for (int mi = 0; mi < 2; mi++) {
        union { s4b v; unsigned u[2]; } p;
        p.u[0] = __builtin_amdgcn_perm(fbits(sacc[mi][si][1]), fbits(sacc[mi][si][0]), 0x07060302u);
        p.u[1] = __builtin_amdgcn_perm(fbits(sacc[mi][si][3]), fbits(sacc[mi][si][2]), 0x07060302u);
        pb[mi] = p.v;
      }
      #pragma unroll
      for (int dt = 0; dt < 4; dt++) {
        int r = dt * 16 + l15;
        int c = (si << 1) + (quad >> 1);
        int cl = (c & 8) | ((c ^ (r & 7)) & 7);
        s4b vf = *(const s4b*)&lV[r * 128 + (cl << 3) + ((quad & 1) << 2)];
        oacc[0][dt] = __builtin_amdgcn_mfma_f32_16x16x16bf16_1k(vf, pb[0], oacc[0][dt], 0, 0, 0);
        oacc[1][dt] = __builtin_amdgcn_mfma_f32_16x16x16bf16_1k(vf, pb[1], oacc[1][dt], 0, 0, 0);
      }
    }
    __syncthreads();
  }

  u16* Ob = Op + (size_t)(z * 32 + bh) * S_TOT * DH;
  float2* mlb = ml + (size_t)(z * 32 + bh) * S_TOT;
  #pragma unroll
  for (int mi = 0; mi < 2; mi++) {
    int qg = q0 + wave * 32 + mi * 16 + l15;
    size_t base = (size_t)qg * DH;
    #pragma unroll
    for (int dt = 0; dt < 4; dt++) {
      s4b o;
      #pragma unroll
      for (int r = 0; r < 4; r++) o[r] = (short)f2bf(oacc[mi][dt][r]);
      *(s4b*)&Ob[base + dt * 16 + quad * 4] = o;
    }
    if (quad == 0) mlb[qg] = make_float2(mst[mi], lst[mi]);
  }
}

// ---------------- combine 3 KV-split partials ----------------
__global__ __launch_bounds__(256)
void attn_combine(const u16* __restrict__ Op, const float2* __restrict__ ml,
                  u16* __restrict__ O) {
  int tid = threadIdx.x;
  int row = blockIdx.x * 4 + (tid >> 6);
  int d = tid & 63;
  const size_t ZS = (size_t)32 * S_TOT;
  float2 a0 = ml[row], a1 = ml[ZS + row], a2 = ml[2 * ZS + row];
  float M = fmaxf(a0.x, fmaxf(a1.x, a2.x));
  float w0 = fexp2(a0.x - M), w1 = fexp2(a1.x - M), w2 = fexp2(a2.x - M);
  float L = w0 * a0.y + w1 * a1.y + w2 * a2.y;
  size_t stride = ZS * DH;
  size_t idx = (size_t)row * DH + d;
  float o = w0 * bf2f(Op[idx]) + w1 * bf2f(Op[stride + idx]) + w2 * bf2f(Op[2 * stride + idx]);
  o /= L;
  int bh = row / S_TOT, q = row - bh * S_TOT;
  int b = bh >> 4, h = bh & 15;
  O[(((size_t)(b * S_TOT + q)) << 10) + h * 64 + d] = f2bf(o);
}

// ---------------- launch ----------------
extern "C" void kernel_launch(void* const* d_in, const int* in_sizes, int n_in,
                              void* d_out, int out_size, void* d_ws, size_t ws_size,
                              hipStream_t stream) {
  const float* x       = (const float*)d_in[0];
  const float* mod     = (const float*)d_in[1];
  const float* cond    = (const float*)d_in[2];
  const float* w_adaln = (const float*)d_in[3];
  const float* b_adaln = (const float*)d_in[4];
  const float* w_qkv   = (const float*)d_in[5];
  const float* b_qkv   = (const float*)d_in[6];
  const float* w_proj  = (const float*)d_in[7];
  const float* b_proj  = (const float*)d_in[8];
  const float* w_s1    = (const float*)d_in[9];
  const float* b_s1    = (const float*)d_in[10];
  const float* w_s2    = (const float*)d_in[11];
  const float* b_s2    = (const float*)d_in[12];
  const float* w_d1    = (const float*)d_in[13];
  const float* b_d1    = (const float*)d_in[14];
  const float* w_d2    = (const float*)d_in[15];
  const float* b_d2    = (const float*)d_in[16];

  float* outx = (float*)d_out;
  float* outc = outx + (size_t)2 * N_SEQ * C_DIM;

  char* w = (char*)d_ws;
  auto alloc = [&](size_t bytes) { char* p = w; w += (bytes + 255) & ~(size_t)255; return p; };
  float* m_ws  = (float*)alloc(12288 * 4);
  u16* wqkvT   = (u16*)alloc((size_t)3072 * 1024 * 2);
  u16* wprojT  = (u16*)alloc((size_t)1024 * 1024 * 2);
  u16* ws1T    = (u16*)alloc((size_t)4096 * 1024 * 2);
  u16* ws2T    = (u16*)alloc((size_t)4096 * 1024 * 2);
  u16* wd1T    = (u16*)alloc((size_t)4096 * 1024 * 2);
  u16* wd2T    = (u16*)alloc((size_t)4096 * 1024 * 2);
  u16* joint   = (u16*)alloc((size_t)4608 * 1024 * 2);
  u16* Qb      = (u16*)alloc((size_t)4718592 * 2);
  u16* Kb      = (u16*)alloc((size_t)4718592 * 2);
  u16* Vb      = (u16*)alloc((size_t)4718592 * 2);
  u16* Vtb     = (u16*)alloc((size_t)4718592 * 2);
  u16* h1      = (u16*)alloc((size_t)4608 * 4096 * 2);
  u16* xln2 = Qb;
  u16* cln2 = Kb;
  u16* attn_out = joint;
  u16* O_part = h1;
  float2* ml = (float2*)(h1 + (size_t)3 * 32 * S_TOT * DH);

  size_t needed = (size_t)(w - (char*)d_ws);
  if (needed > ws_size) {
    hipMemsetAsync(d_out, 0, (size_t)out_size * 4, stream);
    return;
  }

  hipMemsetAsync(m_ws, 0, 12288 * 4, stream);
  adaln_mod<<<dim3(24, 2, 8), 256, 0, stream>>>(mod, w_adaln, m_ws);

  wtrans_all<<<20480, 256, 0, stream>>>(w_qkv, w_proj, w_s1, w_s2, w_d1, w_d2,
                                        wqkvT, wprojT, ws1T, ws2T, wd1T, wd2T);

  ln_mod<0><<<4608, 256, 0, stream>>>(x, cond, m_ws, b_adaln, nullptr, nullptr, joint);

  gemm_k<0, 128><<<dim3(24, 36), 256, 0, stream>>>(joint, wqkvT, b_qkv, 1024,
      nullptr, nullptr, nullptr, nullptr, nullptr, nullptr, Qb, Kb, Vb);

  vtrans<<<dim3(36, 32), 256, 0, stream>>>(Vb, Vtb);
  flash_attn<<<dim3(18, 32, 3), 256, 0, stream>>>(Qb, Kb, Vtb, O_part, ml);
  attn_combine<<<18432, 256, 0, stream>>>(O_part, ml, attn_out);

  gemm_k<1, 64><<<dim3(8, 72), 256, 0, stream>>>(attn_out, wprojT, b_proj, 1024,
      m_ws, b_adaln, x, cond, outx, outc, nullptr, nullptr, nullptr);

  ln_mod<3072><<<4608, 256, 0, stream>>>(outx, outc, m_ws, b_adaln, xln2, cln2, nullptr);

  mlp1<<<dim3(32, 36), 256, 0, stream>>>(xln2, cln2, ws1T, wd1T, b_s1, b_d1, h1);
  mlp2<<<dim3(8, 72), 256, 0, stream>>>(h1, ws2T, wd2T, b_s2, b_d2,
                                        m_ws, b_adaln, outx, outc);
}